// Round 1
// baseline (278.265 us; speedup 1.0000x reference)
//
#include <hip/hip_runtime.h>
#include <math.h>

// Problem constants (B,H,W,C,F fixed by setup_inputs)
#define Bb 4
#define Hh 128
#define Ww 256
#define Cc 64
#define Ff 128
#define INH 130   // H+2 (padded)
#define INW 258   // W+2 (padded)

typedef __attribute__((ext_vector_type(8))) __bf16 bf16x8;
typedef __attribute__((ext_vector_type(4))) float floatx4;

__device__ __forceinline__ unsigned short f2bf(float f) {
  unsigned int u = __float_as_uint(f);
  unsigned int r = u + 0x7fffu + ((u >> 16) & 1u);   // RNE
  return (unsigned short)(r >> 16);
}

// ---------------------------------------------------------------------------
// Prep kernel: (a) transpose conv kernel [576][128] f32 -> kT[128][576] bf16
//              (b) offset table offtab[h][tap][2] in fp64 (faithful numpy port;
//                  fp32 would flip the ux>0 branch at h=0 where cos(pi/2)~6e-17)
// ---------------------------------------------------------------------------
__global__ void prep_kernel(const float* __restrict__ kmat,
                            float* __restrict__ offtab,
                            unsigned short* __restrict__ kT) {
  int gid = blockIdx.x * 256 + threadIdx.x;
  if (gid < 576 * 128) {
    int f = gid & 127;        // f contiguous in source -> coalesced reads
    int k = gid >> 7;
    kT[f * 576 + k] = f2bf(kmat[gid]);
  }
  if (gid < Hh * 9) {
    int h = gid / 9;
    int j = gid - h * 9;
    const double pi = 3.14159265358979323846;
    double unit_w = 2.0 * pi / (double)Ww;
    double unit_h = pi / (2.0 * (double)Hh);   // skydome
    double rho = tan(unit_w);                  // dilation = 1
    double theta = ((double)(Ww / 2) - 0.5 * (double)Ww) * unit_w;  // = 0
    double phi = ((double)Hh - (double)h) * unit_h;
    double cph = cos(phi), sph = sin(phi);
    double cth = cos(theta), sth = sin(theta);
    double pux = cph * cth, puy = sph, puz = cph * sth;
    // t_x = cross([0,1,0], p_u) = (puz, 0, -pux)
    double txx = puz, txy = 0.0, txz = -pux;
    // t_y = cross(p_u, t_x)
    double tyx = puy * txz - puz * txy;
    double tyy = puz * txx - pux * txz;
    double tyz = pux * txy - puy * txx;
    const int r0t[9] = {1, 1, 1, 0, 0, 0, -1, -1, -1};
    const int r1t[9] = {-1, 0, 1, -1, 0, 1, -1, 0, 1};
    auto proj = [&](int r0, int r1, double& xr, double& yr) {
      double ux = pux + rho * ((double)r0 * txx + (double)r1 * tyx);
      double uy = puy + rho * ((double)r0 * txy + (double)r1 * tyy);
      double uz = puz + rho * ((double)r0 * txz + (double)r1 * tyz);
      double base = atan2(uz, ux);
      double th;
      if (ux > 0.0)        th = base;
      else if (ux < 0.0)   th = (uz >= 0.0) ? base + pi : base - pi;
      else                 th = (uz > 0.0) ? pi * 0.5 : -pi * 0.5;
      double ph = asin(uy);
      xr = (th / pi + 1.0) * 0.5 * (double)Ww;
      yr = (1.0 - 2.0 * ph / pi) * (double)Hh;   // skydome
    };
    double xc, yc, xj, yj;
    proj(0, 0, xc, yc);                    // center tap (j=4)
    proj(r0t[j], r1t[j], xj, yj);
    offtab[gid * 2 + 0] = (float)(xj - xc);   // channel 0 (x_r diff) -> added to y
    offtab[gid * 2 + 1] = (float)(yj - yc);   // channel 1 (y_r diff) -> added to x
  }
}

// ---------------------------------------------------------------------------
// Fused gather + bilinear + implicit GEMM (bf16 MFMA 16x16x32) + bias + relu.
// Block = (b, h, 128-wide w tile) x all F=128. 4 waves, each 64x64 (4x4 frags).
// K-loop = 9 taps x 64 channels (BK=64, two 32-chunks per tap).
// ---------------------------------------------------------------------------
__global__ __launch_bounds__(256) void fused_kernel(
    const float* __restrict__ in, const float* __restrict__ bias,
    const unsigned short* __restrict__ kT, const float* __restrict__ offtab,
    float* __restrict__ out) {
  // stride 72 bf16 = 144 B = 36 banks -> frag reads only 2-way conflicted (free)
  __shared__ unsigned short lA[128 * 72];
  __shared__ unsigned short lB[128 * 72];

  int bx = blockIdx.x;
  int wt = bx & 1;
  int h  = (bx >> 1) & 127;
  int b  = bx >> 8;
  int w0 = wt << 7;

  int tid  = threadIdx.x;
  int lane = tid & 63;
  int wave = tid >> 6;
  int m_base = (wave >> 1) << 6;
  int n_base = (wave & 1) << 6;
  int l15  = lane & 15;
  int quad = lane >> 4;

  floatx4 acc[4][4];
#pragma unroll
  for (int i = 0; i < 4; i++)
#pragma unroll
    for (int j = 0; j < 4; j++) acc[i][j] = (floatx4){0.f, 0.f, 0.f, 0.f};

  const float* inb = in + (size_t)b * Hh * Ww * Cc;
  int c4 = (tid & 15) << 2;           // channel group this thread stages

  for (int tap = 0; tap < 9; tap++) {
    // ---- per-(h,tap) scalars (wave-uniform): y, rows, y-weights ----
    float off0 = offtab[(h * 9 + tap) * 2 + 0];
    float off1 = offtab[(h * 9 + tap) * 2 + 1];
    float dyk = (float)(tap / 3), dxk = (float)(tap % 3);
    float y = (float)h + dyk + off0;
    y = fminf(fmaxf(y, 0.f), (float)(INH - 1));
    int y0i = (int)floorf(y);
    int y1i = y0i + 1;
    y0i = min(max(y0i, 0), INH - 1);
    y1i = min(max(y1i, 0), INH - 1);
    float wy0 = (float)y1i - y;
    float wy1 = y - (float)y0i;
    bool y0in = (y0i >= 1 && y0i <= Hh);
    bool y1in = (y1i >= 1 && y1i <= Hh);
    const float* row0 = inb + (size_t)(y0i - 1) * Ww * Cc;
    const float* row1 = inb + (size_t)(y1i - 1) * Ww * Cc;

    // ---- stage A: 128 w x 64 c bilinear pixels -> bf16 LDS ----
#pragma unroll
    for (int wp = 0; wp < 8; wp++) {
      int wl = (tid >> 4) + (wp << 4);
      float x = (float)(w0 + wl) + dxk + off1;
      if (x < 0.f) x += (float)INW;                 // wrap (faithful order)
      if (x > (float)(INW - 1)) x -= (float)INW;
      int x0i = (int)floorf(x);
      int x1i = x0i + 1;
      x0i = min(max(x0i, 0), INW - 1);
      x1i = min(max(x1i, 0), INW - 1);
      float wx0 = (float)x1i - x;                   // weights from clipped ints
      float wx1 = x - (float)x0i;
      bool x0in = (x0i >= 1 && x0i <= Ww);
      bool x1in = (x1i >= 1 && x1i <= Ww);
      float4 p00 = {0, 0, 0, 0}, p01 = {0, 0, 0, 0};
      float4 p10 = {0, 0, 0, 0}, p11 = {0, 0, 0, 0};
      if (y0in && x0in) p00 = *(const float4*)(row0 + (x0i - 1) * Cc + c4);
      if (y0in && x1in) p01 = *(const float4*)(row0 + (x1i - 1) * Cc + c4);
      if (y1in && x0in) p10 = *(const float4*)(row1 + (x0i - 1) * Cc + c4);
      if (y1in && x1in) p11 = *(const float4*)(row1 + (x1i - 1) * Cc + c4);
      float4 p;
      p.x = wy0 * (wx0 * p00.x + wx1 * p01.x) + wy1 * (wx0 * p10.x + wx1 * p11.x);
      p.y = wy0 * (wx0 * p00.y + wx1 * p01.y) + wy1 * (wx0 * p10.y + wx1 * p11.y);
      p.z = wy0 * (wx0 * p00.z + wx1 * p01.z) + wy1 * (wx0 * p10.z + wx1 * p11.z);
      p.w = wy0 * (wx0 * p00.w + wx1 * p01.w) + wy1 * (wx0 * p10.w + wx1 * p11.w);
      uint2 st;
      st.x = (unsigned int)f2bf(p.x) | ((unsigned int)f2bf(p.y) << 16);
      st.y = (unsigned int)f2bf(p.z) | ((unsigned int)f2bf(p.w) << 16);
      *(uint2*)(&lA[wl * 72 + c4]) = st;
    }

    // ---- stage B: kT[f][tap*64 .. +64] -> lB[f][0..64] (coalesced) ----
    {
      int f = tid >> 1, seg = tid & 1;
      const unsigned short* src = kT + f * 576 + tap * 64 + seg * 32;
      unsigned short* dst = &lB[f * 72 + seg * 32];
#pragma unroll
      for (int i = 0; i < 4; i++)
        *(uint4*)(dst + i * 8) = *(const uint4*)(src + i * 8);
    }

    __syncthreads();

    // ---- MFMA: 2 K-chunks of 32, 4x4 16x16 tiles per wave ----
#pragma unroll
    for (int kk = 0; kk < 2; kk++) {
      bf16x8 afrag[4], bfrag[4];
#pragma unroll
      for (int mi = 0; mi < 4; mi++)
        afrag[mi] = *(const bf16x8*)&lA[(m_base + mi * 16 + l15) * 72 + kk * 32 + quad * 8];
#pragma unroll
      for (int ni = 0; ni < 4; ni++)
        bfrag[ni] = *(const bf16x8*)&lB[(n_base + ni * 16 + l15) * 72 + kk * 32 + quad * 8];
#pragma unroll
      for (int mi = 0; mi < 4; mi++)
#pragma unroll
        for (int ni = 0; ni < 4; ni++)
          acc[mi][ni] = __builtin_amdgcn_mfma_f32_16x16x32_bf16(
              afrag[mi], bfrag[ni], acc[mi][ni], 0, 0, 0);
    }
    __syncthreads();
  }

  // ---- epilogue: bias + relu, fp32 stores (C/D: col=lane&15, row=quad*4+r) ----
  size_t outbase = ((size_t)(b * Hh + h) * Ww + w0);
#pragma unroll
  for (int ni = 0; ni < 4; ni++) {
    int f = n_base + ni * 16 + l15;
    float bv = bias[f];
#pragma unroll
    for (int mi = 0; mi < 4; mi++) {
#pragma unroll
      for (int r = 0; r < 4; r++) {
        int m = m_base + mi * 16 + quad * 4 + r;
        out[(outbase + m) * Ff + f] = fmaxf(acc[mi][ni][r] + bv, 0.f);
      }
    }
  }
}

extern "C" void kernel_launch(void* const* d_in, const int* in_sizes, int n_in,
                              void* d_out, int out_size, void* d_ws, size_t ws_size,
                              hipStream_t stream) {
  const float* in   = (const float*)d_in[0];
  const float* kmat = (const float*)d_in[1];
  const float* bias = (const float*)d_in[2];
  float* out = (float*)d_out;

  // workspace layout: offtab (H*9*2 f32 = 9216 B, 16B-aligned) | kT (128x576 bf16)
  float* offtab = (float*)d_ws;
  unsigned short* kT = (unsigned short*)((char*)d_ws + Hh * 9 * 2 * sizeof(float));
  if (ws_size < (size_t)(Hh * 9 * 2 * sizeof(float) + 128 * 576 * sizeof(unsigned short)))
    return;  // workspace too small (should not happen)

  prep_kernel<<<288, 256, 0, stream>>>(kmat, offtab, kT);
  fused_kernel<<<Bb * Hh * (Ww / 128), 256, 0, stream>>>(in, bias, kT, offtab, out);
}

// Round 2
// 153.520 us; speedup vs baseline: 1.8126x; 1.8126x over previous
//
#include <hip/hip_runtime.h>
#include <math.h>

#define Bb 4
#define Hh 128
#define Ww 256
#define Cc 64
#define Ff 128
#define INH 130   // H+2
#define INW 258   // W+2

#define WSLOT 72   // shorts per column (64 + 8 pad): 144B stride, 16B-aligned, 2-way banks
#define WCOLS 132  // cols 0..130 = data window, col 131 = dedicated zero column

typedef __attribute__((ext_vector_type(8))) __bf16 bf16x8;
typedef __attribute__((ext_vector_type(4))) float floatx4;

__device__ __forceinline__ unsigned short f2bf(float f) {
  unsigned int u = __float_as_uint(f);
  unsigned int r = u + 0x7fffu + ((u >> 16) & 1u);   // RNE
  return (unsigned short)(r >> 16);
}

// ---------------------------------------------------------------------------
// Prep: kernel transpose to bf16 + fp64 offset table (fp32 would flip the
// ux>0 branch at h=0 where cos(pi/2)~6e-17 -> half-width x shift).
// ---------------------------------------------------------------------------
__global__ void prep_kernel(const float* __restrict__ kmat,
                            float* __restrict__ offtab,
                            unsigned short* __restrict__ kT) {
  int gid = blockIdx.x * 256 + threadIdx.x;
  if (gid < 576 * 128) {
    int f = gid & 127;
    int k = gid >> 7;
    kT[f * 576 + k] = f2bf(kmat[gid]);
  }
  if (gid < Hh * 9) {
    int h = gid / 9;
    int j = gid - h * 9;
    const double pi = 3.14159265358979323846;
    double unit_w = 2.0 * pi / (double)Ww;
    double unit_h = pi / (2.0 * (double)Hh);
    double rho = tan(unit_w);
    double theta = ((double)(Ww / 2) - 0.5 * (double)Ww) * unit_w;
    double phi = ((double)Hh - (double)h) * unit_h;
    double cph = cos(phi), sph = sin(phi);
    double cth = cos(theta), sth = sin(theta);
    double pux = cph * cth, puy = sph, puz = cph * sth;
    double txx = puz, txy = 0.0, txz = -pux;
    double tyx = puy * txz - puz * txy;
    double tyy = puz * txx - pux * txz;
    double tyz = pux * txy - puy * txx;
    const int r0t[9] = {1, 1, 1, 0, 0, 0, -1, -1, -1};
    const int r1t[9] = {-1, 0, 1, -1, 0, 1, -1, 0, 1};
    auto proj = [&](int r0, int r1, double& xr, double& yr) {
      double ux = pux + rho * ((double)r0 * txx + (double)r1 * tyx);
      double uy = puy + rho * ((double)r0 * txy + (double)r1 * tyy);
      double uz = puz + rho * ((double)r0 * txz + (double)r1 * tyz);
      double base = atan2(uz, ux);
      double th;
      if (ux > 0.0)        th = base;
      else if (ux < 0.0)   th = (uz >= 0.0) ? base + pi : base - pi;
      else                 th = (uz > 0.0) ? pi * 0.5 : -pi * 0.5;
      double ph = asin(uy);
      xr = (th / pi + 1.0) * 0.5 * (double)Ww;
      yr = (1.0 - 2.0 * ph / pi) * (double)Hh;
    };
    double xc, yc, xj, yj;
    proj(0, 0, xc, yc);
    proj(r0t[j], r1t[j], xj, yj);
    offtab[gid * 2 + 0] = (float)(xj - xc);   // added to y (faithful swap)
    offtab[gid * 2 + 1] = (float)(yj - yc);   // added to x
  }
}

// ---------------------------------------------------------------------------
// Fused: per (b,h,128-w tile). Per tap:
//  phase 1 (fill): column window hm[j] = q00*R0[j]+q01*R0[j+1]+q10*R1[j]+q11*R1[j+1]
//    (x-weights are block-uniform since frac(w + dxk + off1) is w-independent;
//     y-pad folded into q's; x-pad masked; wrap handled by mod-258 column ids;
//     double-wrap lanes resolve to pad-column pairs == exact 0)
//    + stage B-tile. Loads are unconditional & contiguous -> pipelined.
//  phase 2: MFMA, A-frags = raw ds_read_b128 from window at per-lane slot.
// ---------------------------------------------------------------------------
__global__ __launch_bounds__(256, 4) void fused_kernel(
    const float* __restrict__ in, const float* __restrict__ bias,
    const unsigned short* __restrict__ kT, const float* __restrict__ offtab,
    float* __restrict__ out) {
  __shared__ unsigned short winH[WCOLS * WSLOT];
  __shared__ unsigned short lB[128 * WSLOT];

  // XCD swizzle: each XCD gets one b and a contiguous h-range (~4.4MB == L2)
  int lidx = ((blockIdx.x & 7) << 7) | (blockIdx.x >> 3);
  int wt = lidx & 1;
  int h  = (lidx >> 1) & 127;
  int b  = lidx >> 8;
  int w0 = wt << 7;

  int tid  = threadIdx.x;
  int lane = tid & 63;
  int wave = tid >> 6;
  int m_base = (wave >> 1) << 6;
  int n_base = (wave & 1) << 6;
  int l15  = lane & 15;
  int quad = lane >> 4;

  floatx4 acc[4][4];
#pragma unroll
  for (int i = 0; i < 4; i++)
#pragma unroll
    for (int j = 0; j < 4; j++) acc[i][j] = (floatx4){0.f, 0.f, 0.f, 0.f};

  const float* inb = in + (size_t)b * Hh * Ww * Cc;

  for (int tap = 0; tap < 9; tap++) {
    float off0 = offtab[(h * 9 + tap) * 2 + 0];
    float off1 = offtab[(h * 9 + tap) * 2 + 1];
    float dyk = (float)(tap / 3), dxk = (float)(tap % 3);

    // ---- y side (wave-uniform): rows + weights, pad folded into weights ----
    float y = (float)h + dyk + off0;
    y = fminf(fmaxf(y, 0.f), (float)(INH - 1));
    int y0i = (int)floorf(y);
    int y1i = y0i + 1;
    y0i = min(max(y0i, 0), INH - 1);
    y1i = min(max(y1i, 0), INH - 1);
    float wy0 = (float)y1i - y;
    float wy1 = y - (float)y0i;
    if (!(y0i >= 1 && y0i <= Hh)) wy0 = 0.f;
    if (!(y1i >= 1 && y1i <= Hh)) wy1 = 0.f;
    const float* row0 = inb + (size_t)min(max(y0i - 1, 0), Hh - 1) * Ww * Cc;
    const float* row1 = inb + (size_t)min(max(y1i - 1, 0), Hh - 1) * Ww * Cc;

    // ---- x side: block-uniform fractional weights + window base ----
    float xrep = (float)w0 + dxk + off1;
    float flo  = floorf(xrep);
    int jb = (int)flo - 1;
    float fr = xrep - flo;              // uniform frac across w (±1ulp, benign)
    float q00 = wy0 * (1.f - fr), q01 = wy0 * fr;
    float q10 = wy1 * (1.f - fr), q11 = wy1 * fr;

    // ---- per-lane slots for this tap (before barrier; LDS not touched) ----
    int slotv[4];
#pragma unroll
    for (int mi = 0; mi < 4; mi++) {
      int w = m_base + mi * 16 + l15;
      float x = (float)(w0 + w) + dxk + off1;   // ref op order
      if (x < 0.f) x += (float)INW;
      if (x > (float)(INW - 1)) x -= (float)INW;
      int x0i = (int)floorf(x);
      int s = x0i - jb;
      if (s < 0) s += INW;      // single-wrap lanes -> mod lookup
      if (s > 131) s = 131;     // anything else -> zero column
      slotv[mi] = s;
    }

    // ---- fill phase: 132 cols x 16 ch-groups; unconditional float4 loads ----
#pragma unroll 3
    for (int it = 0; it < 9; it++) {
      int task = tid + (it << 8);
      if (task < WCOLS * 16) {
        int j  = task >> 4;
        int c4 = (task & 15) << 2;
        int col = jb + j;
        if (col < 0) col += INW;
        if (col > INW - 1) col -= INW;
        int ncol = jb + j + 1;
        if (ncol < 0) ncol += INW;
        if (ncol > INW - 1) ncol -= INW;
        bool cok = (col >= 1) & (col <= Ww) & (j < 131);
        bool nok = (ncol >= 1) & (ncol <= Ww) & (j < 131);
        int ci = min(max(col - 1, 0), Ww - 1);
        int ni = min(max(ncol - 1, 0), Ww - 1);
        float4 a0 = *(const float4*)(row0 + ci * Cc + c4);
        float4 a1 = *(const float4*)(row0 + ni * Cc + c4);
        float4 b0 = *(const float4*)(row1 + ci * Cc + c4);
        float4 b1 = *(const float4*)(row1 + ni * Cc + c4);
        float m0 = cok ? 1.f : 0.f, m1 = nok ? 1.f : 0.f;
        float w00 = q00 * m0, w01 = q01 * m1, w10 = q10 * m0, w11 = q11 * m1;
        float4 p;
        p.x = w00 * a0.x + w01 * a1.x + w10 * b0.x + w11 * b1.x;
        p.y = w00 * a0.y + w01 * a1.y + w10 * b0.y + w11 * b1.y;
        p.z = w00 * a0.z + w01 * a1.z + w10 * b0.z + w11 * b1.z;
        p.w = w00 * a0.w + w01 * a1.w + w10 * b0.w + w11 * b1.w;
        uint2 st;
        st.x = (unsigned int)f2bf(p.x) | ((unsigned int)f2bf(p.y) << 16);
        st.y = (unsigned int)f2bf(p.z) | ((unsigned int)f2bf(p.w) << 16);
        *(uint2*)(&winH[j * WSLOT + c4]) = st;
      }
    }

    // ---- stage B tile: kT[f][tap*64..+64] ----
    {
      int f = tid >> 1, seg = tid & 1;
      const unsigned short* src = kT + f * 576 + tap * 64 + seg * 32;
      unsigned short* dst = &lB[f * WSLOT + seg * 32];
#pragma unroll
      for (int i = 0; i < 4; i++)
        *(uint4*)(dst + i * 8) = *(const uint4*)(src + i * 8);
    }

    __syncthreads();

    // ---- MFMA: A-frags are pure b128 reads from the premixed window ----
#pragma unroll
    for (int kk = 0; kk < 2; kk++) {
      bf16x8 afrag[4], bfrag[4];
#pragma unroll
      for (int mi = 0; mi < 4; mi++)
        afrag[mi] = *(const bf16x8*)&winH[slotv[mi] * WSLOT + kk * 32 + quad * 8];
#pragma unroll
      for (int ni = 0; ni < 4; ni++)
        bfrag[ni] = *(const bf16x8*)&lB[(n_base + ni * 16 + l15) * WSLOT + kk * 32 + quad * 8];
#pragma unroll
      for (int mi = 0; mi < 4; mi++)
#pragma unroll
        for (int ni = 0; ni < 4; ni++)
          acc[mi][ni] = __builtin_amdgcn_mfma_f32_16x16x32_bf16(
              afrag[mi], bfrag[ni], acc[mi][ni], 0, 0, 0);
    }
    __syncthreads();
  }

  // ---- epilogue: bias + relu (C/D: col=lane&15, row=quad*4+r) ----
  size_t outbase = ((size_t)(b * Hh + h) * Ww + w0);
#pragma unroll
  for (int ni = 0; ni < 4; ni++) {
    int f = n_base + ni * 16 + l15;
    float bv = bias[f];
#pragma unroll
    for (int mi = 0; mi < 4; mi++) {
#pragma unroll
      for (int r = 0; r < 4; r++) {
        int m = m_base + mi * 16 + quad * 4 + r;
        out[(outbase + m) * Ff + f] = fmaxf(acc[mi][ni][r] + bv, 0.f);
      }
    }
  }
}

extern "C" void kernel_launch(void* const* d_in, const int* in_sizes, int n_in,
                              void* d_out, int out_size, void* d_ws, size_t ws_size,
                              hipStream_t stream) {
  const float* in   = (const float*)d_in[0];
  const float* kmat = (const float*)d_in[1];
  const float* bias = (const float*)d_in[2];
  float* out = (float*)d_out;

  float* offtab = (float*)d_ws;
  unsigned short* kT = (unsigned short*)((char*)d_ws + Hh * 9 * 2 * sizeof(float));
  if (ws_size < (size_t)(Hh * 9 * 2 * sizeof(float) + 128 * 576 * sizeof(unsigned short)))
    return;

  prep_kernel<<<288, 256, 0, stream>>>(kmat, offtab, kT);
  fused_kernel<<<Bb * Hh * (Ww / 128), 256, 0, stream>>>(in, bias, kT, offtab, out);
}